// Round 1
// baseline (91.619 us; speedup 1.0000x reference)
//
#include <hip/hip_runtime.h>
#include <math.h>

#define HID 128
#define SPB 64    // samples per chunk per block
#define TPB 512   // 8 waves; 2 blocks/CU (74.5KB LDS) -> two barrier domains
#define GRIDB 512 // persistent

typedef __bf16 bf16;
typedef bf16 bf16x8 __attribute__((ext_vector_type(8)));
typedef bf16 bf16x4 __attribute__((ext_vector_type(4)));
typedef float floatx4 __attribute__((ext_vector_type(4)));

// rcp-based tanh: mul, exp2(trans), add, rcp(trans), fma  (~5 ops vs ~14 with IEEE div)
// rcp is ~1ulp; downstream values are truncated to bf16, so error is invisible.
__device__ __forceinline__ float fast_tanh(float x) {
    float e = __builtin_amdgcn_exp2f(x * 2.885390081777927f); // exp(2x)
    return 1.0f - 2.0f * __builtin_amdgcn_rcpf(e + 1.0f);
}

// ALL-TRANSPOSED formulation. MFMA 16x16x32 layouts:
//   A-frag: lane holds A[m=lane&15][k=quad*8+idx]
//   B-frag: lane holds B[k=quad*8+idx][n=lane&15]
//   C/D:    lane/reg holds D[row=quad*4+reg][col=lane&15]
// GEMM1t: Z2^T = W2^T @ H1^T   (A=W2^T frags in LDS, B=H1^T frags in LDS)
// GEMM2t: S^T  = W2 @ G2^T     (A=W2 rows in REGS, hoisted; B=G2^T in LDS)
// GEMM3t: dV^T = W1 @ G1^T     (A=W1 reg frag, B=G1^T IN-PLACE in sH1, same-wave)
// Barriers per chunk: B (sH1 ready), C (sG2 ready), F (sDV+state ready).
// Old barrier D removed: phase5 reads+writes only its OWN (st*4+wlo) slots of
// sH1 (per-lane read-then-write of the same 8B region), and GEMM3 reads those
// same slots same-wave. sG2 is untouched between GEMM2's reads and the next
// chunk's phase3 writes (barriers F,B intervene).
// Wave w (8 waves): wlo=w&3, whi=w>>2.
//   phase1: st=wlo, kt in {2whi,2whi+1}
//   GEMM1t/phase3: jt in {2wlo,2wlo+1}, st in {2whi,2whi+1}
//   GEMM2t/phase5/GEMM3t: it in {2wlo,2wlo+1} (jt2_own=wlo), st in {2whi,2whi+1}

__global__ __launch_bounds__(TPB, 4)
void lnn_kernel(const float* __restrict__ X,
                const float* __restrict__ W1,
                const float* __restrict__ b1,
                const float* __restrict__ b2,
                const float* __restrict__ W3,
                const float* __restrict__ W2,
                float* __restrict__ out,
                int B, int nchunk)
{
    __shared__ __align__(16) bf16 sW2A[16384]; // 32KB W2^T A-frags [(jt*4+kt)*64+l]*8
    __shared__ __align__(16) bf16 sH1 [8192];  // 16KB H1^T B-frags [(st*4+kt)*64+l]*8 (G1^T in-place after phase5)
    __shared__ __align__(16) bf16 sG2 [8192];  // 16KB G2^T B-frags [(st*4+jt2)*64+l]*8
    __shared__ __align__(16) float4 sW1c[HID]; // {W1[0][j],..,W1[3][j]}
    __shared__ float sB1[HID], sB2[HID], sW3[HID];
    __shared__ __align__(16) float sFeat[2][SPB][4];
    __shared__ float sQd[2][SPB][2];
    __shared__ __align__(16) float sDV[4][SPB][4]; // partials per jt2

    const int tid  = threadIdx.x;
    const int w    = tid >> 6;
    const int lane = tid & 63;
    const int lrow = lane & 15;
    const int lq   = lane >> 4;
    const int wlo  = w & 3;
    const int whi  = w >> 2;

    // ---------------- one-time staging ----------------
    if (tid < HID) {
        sW1c[tid] = make_float4(W1[tid], W1[HID + tid], W1[2*HID + tid], W1[3*HID + tid]);
        sB1[tid]  = b1[tid];
    } else if (tid < 2 * HID) {
        sB2[tid - HID] = b2[tid - HID];
        sW3[tid - HID] = W3[tid - HID];
    }
    // W2^T A-frags (column-segment gather), 4 frag lines/thread
    #pragma unroll
    for (int tt = 0; tt < 4; ++tt) {
        int e = tid + tt * TPB;       // 0..2047
        int t = e >> 6, l = e & 63;
        int jt = t >> 2, kt = t & 3;
        int lr = l & 15, q = l >> 4;
        bf16x8 f;
        #pragma unroll
        for (int idx = 0; idx < 8; ++idx)
            f[idx] = (bf16)W2[(32*kt + 8*q + idx) * HID + 16*jt + lr];
        *reinterpret_cast<bf16x8*>(&sW2A[e * 8]) = f;
    }
    // W1 A-frag for GEMM3t, K-range jt2=wlo (rows>=4 zero)
    bf16x8 bW1 = {};
    if (lrow < 4) {
        const float4* wp = reinterpret_cast<const float4*>(&W1[lrow*HID + 32*wlo + 8*lq]);
        float4 a = wp[0], b = wp[1];
        bW1[0]=(bf16)a.x; bW1[1]=(bf16)a.y; bW1[2]=(bf16)a.z; bW1[3]=(bf16)a.w;
        bW1[4]=(bf16)b.x; bW1[5]=(bf16)b.y; bW1[6]=(bf16)b.z; bW1[7]=(bf16)b.w;
    }
    // GEMM2t A-frags: W2 rows from global -> regs, ONCE (loop-invariant; was per-chunk)
    bf16x8 aW2[2][4];
    #pragma unroll
    for (int u = 0; u < 2; ++u) {
        const float* rbase = &W2[(16*(2*wlo + u) + lrow) * HID + 8*lq];
        #pragma unroll
        for (int jt2 = 0; jt2 < 4; ++jt2) {
            const float4* rp = reinterpret_cast<const float4*>(rbase + 32*jt2);
            float4 r0 = rp[0], r1 = rp[1];
            bf16x8 g;
            g[0]=(bf16)r0.x; g[1]=(bf16)r0.y; g[2]=(bf16)r0.z; g[3]=(bf16)r0.w;
            g[4]=(bf16)r1.x; g[5]=(bf16)r1.y; g[6]=(bf16)r1.z; g[7]=(bf16)r1.w;
            aW2[u][jt2] = g;
        }
    }
    // chunk-0 state prefetch (wave 7)
    if (tid >= TPB - SPB) {
        int s  = tid - (TPB - SPB);
        int g  = (int)blockIdx.x * SPB + s;
        int gc = g < B ? g : (B - 1);
        float4 x = reinterpret_cast<const float4*>(X)[gc];
        float s1, c1, s2, c2;
        __sincosf(x.x, &s1, &c1);
        __sincosf(x.y, &s2, &c2);
        sFeat[0][s][0]=s1; sFeat[0][s][1]=c1; sFeat[0][s][2]=s2; sFeat[0][s][3]=c2;
        sQd[0][s][0]=x.z;  sQd[0][s][1]=x.w;
    }
    __syncthreads();

    #pragma unroll 1
    for (int c = 0; c < nchunk; ++c) {
        const int par = c & 1;
        const int s0  = (c * GRIDB + (int)blockIdx.x) * SPB;

        // ---- Phase 1: H1^T B-frags; tile (st=wlo, kt=2whi+h); lane: s=16wlo+lrow ----
        {
            int s = 16 * wlo + lrow;
            float f0 = sFeat[par][s][0], f1 = sFeat[par][s][1];
            float f2 = sFeat[par][s][2], f3 = sFeat[par][s][3];
            #pragma unroll
            for (int h = 0; h < 2; ++h) {
                int kt = 2 * whi + h;
                int jb = 32 * kt + 8 * lq;
                float4 t0 = *reinterpret_cast<const float4*>(&sB1[jb]);
                float4 t1 = *reinterpret_cast<const float4*>(&sB1[jb + 4]);
                float bias[8] = {t0.x,t0.y,t0.z,t0.w,t1.x,t1.y,t1.z,t1.w};
                bf16x8 hf;
                #pragma unroll
                for (int idx = 0; idx < 8; ++idx) {
                    float4 wc = sW1c[jb + idx];
                    float z = bias[idx] + f0*wc.x + f1*wc.y + f2*wc.z + f3*wc.w;
                    hf[idx] = (bf16)fast_tanh(z);
                }
                *reinterpret_cast<bf16x8*>(&sH1[((wlo*4 + kt)*64 + lane)*8]) = hf;
            }
        }
        __syncthreads(); // B: sH1 ready

        // ---- GEMM1t: Z2^T = W2^T @ H1^T ; out tiles (jt=2wlo+t, st=2whi+s) ----
        floatx4 acc[2][2];
        #pragma unroll
        for (int t = 0; t < 2; ++t)
            #pragma unroll
            for (int s = 0; s < 2; ++s) acc[t][s] = floatx4{0.f,0.f,0.f,0.f};
        #pragma unroll
        for (int kt = 0; kt < 4; ++kt) {
            bf16x8 a0 = *reinterpret_cast<const bf16x8*>(&sW2A[(((2*wlo  )*4 + kt)*64 + lane)*8]);
            bf16x8 a1 = *reinterpret_cast<const bf16x8*>(&sW2A[(((2*wlo+1)*4 + kt)*64 + lane)*8]);
            bf16x8 b0 = *reinterpret_cast<const bf16x8*>(&sH1 [(((2*whi  )*4 + kt)*64 + lane)*8]);
            bf16x8 b1 = *reinterpret_cast<const bf16x8*>(&sH1 [(((2*whi+1)*4 + kt)*64 + lane)*8]);
            acc[0][0] = __builtin_amdgcn_mfma_f32_16x16x32_bf16(a0, b0, acc[0][0], 0,0,0);
            acc[0][1] = __builtin_amdgcn_mfma_f32_16x16x32_bf16(a0, b1, acc[0][1], 0,0,0);
            acc[1][0] = __builtin_amdgcn_mfma_f32_16x16x32_bf16(a1, b0, acc[1][0], 0,0,0);
            acc[1][1] = __builtin_amdgcn_mfma_f32_16x16x32_bf16(a1, b1, acc[1][1], 0,0,0);
        }

        // ---- Phase 3: G2^T = (1-tanh^2(Z2+b2))*W3 -> B-frags via ds_write_b64 ----
        #pragma unroll
        for (int t = 0; t < 2; ++t) {
            int jb = 16*(2*wlo + t) + 4*lq;   // j for r=0
            float4 b2v = *reinterpret_cast<const float4*>(&sB2[jb]);
            float4 w3v = *reinterpret_cast<const float4*>(&sW3[jb]);
            float bbv[4] = {b2v.x, b2v.y, b2v.z, b2v.w};
            float w3a[4] = {w3v.x, w3v.y, w3v.z, w3v.w};
            int q2  = 2*t + (lq >> 1);
            int sub = 4 * (lq & 1);
            #pragma unroll
            for (int s = 0; s < 2; ++s) {
                int st = 2*whi + s;
                bf16x4 g;
                #pragma unroll
                for (int r = 0; r < 4; ++r) {
                    float h = fast_tanh(acc[t][s][r] + bbv[r]);
                    g[r] = (bf16)((1.0f - h*h) * w3a[r]);
                }
                *reinterpret_cast<bf16x4*>(&sG2[((st*4 + wlo)*64 + (q2*16 + lrow))*8 + sub]) = g;
            }
        }
        __syncthreads(); // C: sG2 (G2^T) ready

        // ---- GEMM2t: S^T = W2 @ G2^T ; out tiles (it=2wlo+u, st=2whi+s) ----
        #pragma unroll
        for (int t = 0; t < 2; ++t)
            #pragma unroll
            for (int s = 0; s < 2; ++s) acc[t][s] = floatx4{0.f,0.f,0.f,0.f};
        #pragma unroll
        for (int jt2 = 0; jt2 < 4; ++jt2) {
            bf16x8 g0 = *reinterpret_cast<const bf16x8*>(&sG2[(((2*whi  )*4 + jt2)*64 + lane)*8]);
            bf16x8 g1 = *reinterpret_cast<const bf16x8*>(&sG2[(((2*whi+1)*4 + jt2)*64 + lane)*8]);
            acc[0][0] = __builtin_amdgcn_mfma_f32_16x16x32_bf16(aW2[0][jt2], g0, acc[0][0], 0,0,0);
            acc[0][1] = __builtin_amdgcn_mfma_f32_16x16x32_bf16(aW2[0][jt2], g1, acc[0][1], 0,0,0);
            acc[1][0] = __builtin_amdgcn_mfma_f32_16x16x32_bf16(aW2[1][jt2], g0, acc[1][0], 0,0,0);
            acc[1][1] = __builtin_amdgcn_mfma_f32_16x16x32_bf16(aW2[1][jt2], g1, acc[1][1], 0,0,0);
        }
        // (old barrier D removed: phase5 below touches only wave-private sH1 slots)

        // ---- Phase 5: G1^T = (1-h1^2)*S^T, IN-PLACE in sH1 (own slots, b64 RMW) ----
        #pragma unroll
        for (int u = 0; u < 2; ++u) {
            int q2  = 2*u + (lq >> 1);
            int sub = 4 * (lq & 1);
            #pragma unroll
            for (int s = 0; s < 2; ++s) {
                int st  = 2*whi + s;
                int off = ((st*4 + wlo)*64 + (q2*16 + lrow))*8 + sub;
                bf16x4 h4 = *reinterpret_cast<const bf16x4*>(&sH1[off]);
                bf16x4 g;
                #pragma unroll
                for (int r = 0; r < 4; ++r) {
                    float h1 = (float)h4[r];
                    g[r] = (bf16)((1.0f - h1*h1) * acc[u][s][r]);
                }
                *reinterpret_cast<bf16x4*>(&sH1[off]) = g;
            }
        }

        // prefetch next chunk's state (wave 7), overlapped with GEMM3t
        if (tid >= TPB - SPB && c + 1 < nchunk) {
            int s  = tid - (TPB - SPB);
            int g  = ((c + 1) * GRIDB + (int)blockIdx.x) * SPB + s;
            int gc = g < B ? g : (B - 1);
            float4 x = reinterpret_cast<const float4*>(X)[gc];
            float s1, c1, s2, c2;
            __sincosf(x.x, &s1, &c1);
            __sincosf(x.y, &s2, &c2);
            int np = par ^ 1;
            sFeat[np][s][0]=s1; sFeat[np][s][1]=c1; sFeat[np][s][2]=s2; sFeat[np][s][3]=c2;
            sQd[np][s][0]=x.z;  sQd[np][s][1]=x.w;
        }

        // ---- GEMM3t: dV^T partial (jt2=wlo) = W1 @ G1^T (same-wave tiles, from sH1) ----
        {
            bf16x8 g0 = *reinterpret_cast<const bf16x8*>(&sH1[(((2*whi  )*4 + wlo)*64 + lane)*8]);
            bf16x8 g1 = *reinterpret_cast<const bf16x8*>(&sH1[(((2*whi+1)*4 + wlo)*64 + lane)*8]);
            floatx4 d0 = __builtin_amdgcn_mfma_f32_16x16x32_bf16(bW1, g0, floatx4{0.f,0.f,0.f,0.f}, 0,0,0);
            floatx4 d1 = __builtin_amdgcn_mfma_f32_16x16x32_bf16(bW1, g1, floatx4{0.f,0.f,0.f,0.f}, 0,0,0);
            if (lane < 16) { // quad 0: regs r = dV[k=r] for sample s=16st+lane
                *reinterpret_cast<float4*>(&sDV[wlo][16*(2*whi  ) + lane][0]) =
                    make_float4(d0[0], d0[1], d0[2], d0[3]);
                *reinterpret_cast<float4*>(&sDV[wlo][16*(2*whi+1) + lane][0]) =
                    make_float4(d1[0], d1[1], d1[2], d1[3]);
            }
        }
        __syncthreads(); // F: sDV + next-chunk state visible

        // ---- Epilogue: analytic dynamics + 2x2 solve (wave 0, tid<64) ----
        if (tid < SPB) {
            int g = s0 + tid;
            if (g < B) {
                float4 d0 = *reinterpret_cast<const float4*>(&sDV[0][tid][0]);
                float4 d1 = *reinterpret_cast<const float4*>(&sDV[1][tid][0]);
                float4 d2 = *reinterpret_cast<const float4*>(&sDV[2][tid][0]);
                float4 d3 = *reinterpret_cast<const float4*>(&sDV[3][tid][0]);
                float dV0 = d0.x + d1.x + d2.x + d3.x;
                float dV1 = d0.y + d1.y + d2.y + d3.y;
                float dV2 = d0.z + d1.z + d2.z + d3.z;
                float dV3 = d0.w + d1.w + d2.w + d3.w;
                float s1 = sFeat[par][tid][0], c1 = sFeat[par][tid][1];
                float s2 = sFeat[par][tid][2], c2 = sFeat[par][tid][3];
                float w1 = sQd[par][tid][0],  w2 = sQd[par][tid][1];
                float cosD = c1 * c2 + s1 * s2;
                float sinD = s1 * c2 - c1 * s2;
                float dVt1 = dV0 * c1 - dV1 * s1;   // dV/dt1
                float dVt2 = dV2 * c2 - dV3 * s2;   // dV/dt2
                float sT = w1 * w2 * sinD;          // dT/dt1 = -sT, dT/dt2 = +sT
                float cw = sinD * (w2 - w1);
                float rhs1 = (-sT - dVt1) - w2 * cw;
                float rhs2 = ( sT - dVt2) - w1 * cw;
                float det = 2.0f - cosD * cosD;     // det(M) in [1,2]
                float inv = __builtin_amdgcn_rcpf(det);
                float qdd1 = (rhs1 - cosD * rhs2) * inv;
                float qdd2 = (2.0f * rhs2 - cosD * rhs1) * inv;
                *reinterpret_cast<float4*>(&out[4 * g]) = make_float4(w1, w2, qdd1, qdd2);
            }
        }
    }
}

extern "C" void kernel_launch(void* const* d_in, const int* in_sizes, int n_in,
                              void* d_out, int out_size, void* d_ws, size_t ws_size,
                              hipStream_t stream) {
    const float* X  = (const float*)d_in[0];
    const float* W1 = (const float*)d_in[1];
    const float* b1 = (const float*)d_in[2];
    const float* W2 = (const float*)d_in[3];
    const float* b2 = (const float*)d_in[4];
    const float* W3 = (const float*)d_in[5];
    // d_in[6] = b3: constant offset on V, vanishes in all gradients
    float* out = (float*)d_out;
    int B = in_sizes[0] / 4;
    int nchunk = (B + GRIDB * SPB - 1) / (GRIDB * SPB);
    lnn_kernel<<<GRIDB, TPB, 0, stream>>>(X, W1, b1, b2, W3, W2, out, B, nchunk);
}